// Round 13
// baseline (1899.563 us; speedup 1.0000x reference)
//
#include <hip/hip_runtime.h>
#include <hip/hip_bf16.h>
#include <math.h>

#define BB 8
#define TT 512
#define VV 50257
#define NN 768
#define HH 12
#define LL 12
#define MM (BB*TT)   // 4096 rows

typedef short bf16x8 __attribute__((ext_vector_type(8)));
typedef float f32x4 __attribute__((ext_vector_type(4)));
typedef unsigned short us8 __attribute__((ext_vector_type(8)));

__device__ __forceinline__ float bf2f(unsigned short u) {
    union { unsigned int i; float f; } x; x.i = ((unsigned int)u) << 16; return x.f;
}
__device__ __forceinline__ unsigned short f2bf(float f) {
    union { __hip_bfloat16 h; unsigned short u; } c; c.h = __float2bfloat16(f); return c.u;
}

// exact-GELU via A&S 7.1.26 erf (|err|<=1.5e-7, branch-free)
__device__ __forceinline__ float gelu_f(float v) {
    float z = v * 0.70710678118654752f;
    float az = fabsf(z);
    float t = __builtin_amdgcn_rcpf(1.0f + 0.3275911f * az);
    float poly = t * (0.254829592f + t * (-0.284496736f + t * (1.421413741f
               + t * (-1.453152027f + t * 1.061405429f))));
    float erfa = 1.0f - poly * __expf(-z * z);
    float erfv = copysignf(erfa, z);
    return 0.5f * v * (1.0f + erfv);
}

// ---------------- embedding: x0 = wte[idx]+wpe ; hin0 = 2*x0 + se0 ----------------
__global__ __launch_bounds__(512) void embed_kernel(const int* __restrict__ idx,
                                                    const float* __restrict__ wte,
                                                    const float* __restrict__ wpe,
                                                    const float* __restrict__ se0,
                                                    float* __restrict__ x0,
                                                    float* __restrict__ hin)
{
    int row = blockIdx.x * 8 + (threadIdx.x >> 6);
    int lane = threadIdx.x & 63;
    int t = row % TT;
    int tok = idx[row];
    const float* wt = wte + (size_t)tok * NN;
    const float* wp = wpe + (size_t)t * NN;
    float* px = x0 + (size_t)row * NN;
    float* ph = hin + (size_t)row * NN;
#pragma unroll
    for (int i = 0; i < 3; ++i) {
        int c = (lane + i * 64) * 4;
        float4 a = *(const float4*)&wt[c];
        float4 b = *(const float4*)&wp[c];
        float4 e = *(const float4*)&se0[c];
        float4 v = make_float4(a.x + b.x, a.y + b.y, a.z + b.z, a.w + b.w);
        *(float4*)&px[c] = v;
        float4 h2 = make_float4(2.f * v.x + e.x, 2.f * v.y + e.y,
                                2.f * v.z + e.z, 2.f * v.w + e.w);
        *(float4*)&ph[c] = h2;
    }
}

// ---------------- merged weight convert+transpose ----------------
__global__ __launch_bounds__(256) void wconv_all(
    const float* __restrict__ c_attn, const float* __restrict__ attn_proj,
    const float* __restrict__ c_fc, const float* __restrict__ mlp_proj,
    unsigned short* __restrict__ o1, unsigned short* __restrict__ o2,
    unsigned short* __restrict__ o3, unsigned short* __restrict__ o4)
{
    int bid = blockIdx.x;
    const float* W; unsigned short* Wt; int K, Nc, id;
    if (bid < 1728)      { W = c_attn;    Wt = o1; K = 768;  Nc = 2304; id = bid; }
    else if (bid < 2304) { W = attn_proj; Wt = o2; K = 768;  Nc = 768;  id = bid - 1728; }
    else if (bid < 4608) { W = c_fc;      Wt = o3; K = 768;  Nc = 3072; id = bid - 2304; }
    else                 { W = mlp_proj;  Wt = o4; K = 3072; Nc = 768;  id = bid - 4608; }
    int nbx = Nc / 32;
    int n0 = (id % nbx) * 32, k0 = (id / nbx) * 32;

    __shared__ float tile[32][33];
    int tid = threadIdx.x;
    int r = tid >> 3, c4 = (tid & 7) * 4;
    float4 v = *(const float4*)&W[(size_t)(k0 + r) * Nc + n0 + c4];
    tile[r][c4 + 0] = v.x; tile[r][c4 + 1] = v.y;
    tile[r][c4 + 2] = v.z; tile[r][c4 + 3] = v.w;
    __syncthreads();
    ushort4 o;
    o.x = f2bf(tile[c4 + 0][r]); o.y = f2bf(tile[c4 + 1][r]);
    o.z = f2bf(tile[c4 + 2][r]); o.w = f2bf(tile[c4 + 3][r]);
    *(ushort4*)&Wt[(size_t)(n0 + r) * K + k0 + c4] = o;
}

// ---------------- plain layernorm: 1 wave/row, 8 rows/block ----------------
__global__ __launch_bounds__(512) void ln_kernel(
    const float* __restrict__ src, const float* __restrict__ w,
    unsigned short* __restrict__ out)
{
    int row = blockIdx.x * 8 + (threadIdx.x >> 6);
    int lane = threadIdx.x & 63;
    size_t base = (size_t)row * NN;
    float4 v[3];
    float s = 0.f, ss = 0.f;
#pragma unroll
    for (int i = 0; i < 3; ++i) {
        int c = (lane + i * 64) * 4;
        v[i] = *(const float4*)&src[base + c];
        s  += v[i].x + v[i].y + v[i].z + v[i].w;
        ss += v[i].x * v[i].x + v[i].y * v[i].y + v[i].z * v[i].z + v[i].w * v[i].w;
    }
#pragma unroll
    for (int off = 32; off; off >>= 1) { s += __shfl_xor(s, off); ss += __shfl_xor(ss, off); }
    float mu = s / (float)NN;
    float var = ss / (float)NN - mu * mu;
    float rsig = rsqrtf(var + 1e-5f);
#pragma unroll
    for (int i = 0; i < 3; ++i) {
        int c = (lane + i * 64) * 4;
        float4 wv = *(const float4*)&w[c];
        ushort4 u;
        u.x = f2bf((v[i].x - mu) * rsig * wv.x);
        u.y = f2bf((v[i].y - mu) * rsig * wv.y);
        u.z = f2bf((v[i].z - mu) * rsig * wv.z);
        u.w = f2bf((v[i].w - mu) * rsig * wv.w);
        *(ushort4*)&out[base + c] = u;
    }
}

// ---------------- bf16 MFMA GEMM: 3-buffer, depth-1, single barrier, XCD swizzle ----------------
// Operand-swapped: acc = mfma(B, A) computes C^T in-register -> per lane 4 CONSECUTIVE
// cols at one row, so the epilogue packs into float4/ushort4 (16 VMEM insts vs 64).
// EPI: 0 none, 1 gelu, 2 C=res+AB, 3 C=res+AB+x0+se
template<int BN, int EPI, typename OutT>
__global__ __launch_bounds__(256) void mgemm(
    const unsigned short* __restrict__ A, const unsigned short* __restrict__ Bt,
    const float* __restrict__ res, OutT* __restrict__ C, int N, int K,
    const float* __restrict__ x0p, const float* __restrict__ sep)
{
    constexpr int NF = BN / 32;
    __shared__ unsigned short Asb[3][128 * 32];
    __shared__ unsigned short Bsb[3][BN * 32];
    int tid = threadIdx.x;

    int gx = gridDim.x, nwg = gx * gridDim.y;
    int bidl = blockIdx.y * gx + blockIdx.x;
    int cpx = nwg >> 3;
    int sbid = (bidl & 7) * cpx + (bidl >> 3);
    int bx = sbid % gx, by = sbid / gx;

    int row0 = by * 128, col0 = bx * BN;
    const unsigned short* Ap = A + (size_t)row0 * K;
    const unsigned short* Bp = Bt + (size_t)col0 * K;
    int lane = tid & 63, wid = tid >> 6;
    int wr = wid >> 1, wc = wid & 1;
    int fr = lane & 15, fq = lane >> 4;

    f32x4 acc[4][NF];
#pragma unroll
    for (int m = 0; m < 4; ++m)
#pragma unroll
        for (int n = 0; n < NF; ++n)
#pragma unroll
            for (int r = 0; r < 4; ++r) acc[m][n][r] = 0.f;

    int ldso = (tid & 192) * 8;

    auto STAGE = [&](int buf, int k0) {
#pragma unroll
        for (int i = 0; i < 2; ++i) {
            int c = i * 256 + tid;
            __builtin_amdgcn_global_load_lds(
                (const __attribute__((address_space(1))) void*)(Ap + (size_t)(c >> 2) * K + k0 + (c & 3) * 8),
                (__attribute__((address_space(3))) void*)(Asb[buf] + i * 2048 + ldso), 16, 0, 0);
        }
        if constexpr (BN == 128) {
#pragma unroll
            for (int i = 0; i < 2; ++i) {
                int c = i * 256 + tid;
                __builtin_amdgcn_global_load_lds(
                    (const __attribute__((address_space(1))) void*)(Bp + (size_t)(c >> 2) * K + k0 + (c & 3) * 8),
                    (__attribute__((address_space(3))) void*)(Bsb[buf] + i * 2048 + ldso), 16, 0, 0);
            }
        } else {
            __builtin_amdgcn_global_load_lds(
                (const __attribute__((address_space(1))) void*)(Bp + (size_t)(tid >> 2) * K + k0 + (tid & 3) * 8),
                (__attribute__((address_space(3))) void*)(Bsb[buf] + ldso), 16, 0, 0);
        }
    };

    auto COMPUTE = [&](int buf) {
        const unsigned short* Ab = Asb[buf] + (wr * 64 + fr) * 32 + fq * 8;
        const unsigned short* Bb = Bsb[buf] + (wc * (BN / 2) + fr) * 32 + fq * 8;
        bf16x8 af[4], bfr[NF];
#pragma unroll
        for (int m = 0; m < 4; ++m) af[m] = *(const bf16x8*)(Ab + m * 512);
#pragma unroll
        for (int n = 0; n < NF; ++n) bfr[n] = *(const bf16x8*)(Bb + n * 512);
        __builtin_amdgcn_s_setprio(1);
#pragma unroll
        for (int m = 0; m < 4; ++m)
#pragma unroll
            for (int n = 0; n < NF; ++n)
                acc[m][n] = __builtin_amdgcn_mfma_f32_16x16x32_bf16(bfr[n], af[m], acc[m][n], 0, 0, 0);
        __builtin_amdgcn_s_setprio(0);
    };

    int NT = K / 32;
    STAGE(0, 0);
    for (int t = 0; t < NT; ++t) {
        if (t + 1 < NT) {
            STAGE((t + 1) % 3, (t + 1) * 32);
            if constexpr (BN == 128) asm volatile("s_waitcnt vmcnt(4)" ::: "memory");
            else                     asm volatile("s_waitcnt vmcnt(3)" ::: "memory");
        } else {
            asm volatile("s_waitcnt vmcnt(0)" ::: "memory");
        }
        __builtin_amdgcn_s_barrier();
        COMPUTE(t % 3);
    }

    // C^T layout: lane owns row = wr*64 + m*16 + fr, cols = wc*BN/2 + n*16 + fq*4 + (0..3)
#pragma unroll
    for (int m = 0; m < 4; ++m) {
        int row = row0 + wr * 64 + m * 16 + fr;
#pragma unroll
        for (int n = 0; n < NF; ++n) {
            int col = col0 + wc * (BN / 2) + n * 16 + fq * 4;
            float v0 = acc[m][n][0], v1 = acc[m][n][1], v2 = acc[m][n][2], v3 = acc[m][n][3];
            if (EPI == 1) { v0 = gelu_f(v0); v1 = gelu_f(v1); v2 = gelu_f(v2); v3 = gelu_f(v3); }
            if (EPI == 2) {
                float4 rr = *(const float4*)&res[(size_t)row * N + col];
                v0 += rr.x; v1 += rr.y; v2 += rr.z; v3 += rr.w;
            }
            if (EPI == 3) {
                float4 rr = *(const float4*)&res[(size_t)row * N + col];
                float4 xx = *(const float4*)&x0p[(size_t)row * N + col];
                float4 ee = *(const float4*)&sep[col];
                v0 += rr.x + xx.x + ee.x; v1 += rr.y + xx.y + ee.y;
                v2 += rr.z + xx.z + ee.z; v3 += rr.w + xx.w + ee.w;
            }
            if constexpr (sizeof(OutT) == 2) {
                ushort4 u;
                u.x = f2bf(v0); u.y = f2bf(v1); u.z = f2bf(v2); u.w = f2bf(v3);
                *(ushort4*)&C[(size_t)row * N + col] = u;
            } else {
                float4 o = make_float4(v0, v1, v2, v3);
                *(float4*)&C[(size_t)row * N + col] = o;
            }
        }
    }
}

// ---------------- flash MFMA attention: transposed S/O via MFMA operand swap ----------------
__global__ __launch_bounds__(512) void fattn_kernel(const unsigned short* __restrict__ qkv,
                                                    unsigned short* __restrict__ y)
{
    int qt = blockIdx.x, h = blockIdx.y, b = blockIdx.z;
    int tid = threadIdx.x, lane = tid & 63, w = tid >> 6;
    int fr = lane & 15, fq = lane >> 4;

    __shared__ unsigned short Ks[2][64 * 72];
    __shared__ unsigned short Vts[2][64 * 72];
    __shared__ unsigned short Ps[128 * 72];

    int qrow = qt * 128 + w * 16 + fr;
    const unsigned short* qp = qkv + (size_t)(b * TT + qrow) * 2304 + h * 64 + fq * 8;
    bf16x8 qf0 = *(const bf16x8*)qp;
    bf16x8 qf1 = *(const bf16x8*)(qp + 32);

    bool kside = tid < 256;
    int st = tid & 255;
    int sr = st >> 2, sc = (st & 3) * 16;
    const unsigned short* gsrc = qkv + (size_t)(b * TT + sr) * 2304 + (kside ? 768 : 1536) + h * 64 + sc;

    f32x4 acco[4];
#pragma unroll
    for (int n = 0; n < 4; ++n)
#pragma unroll
        for (int r = 0; r < 4; ++r) acco[n][r] = 0.f;
    float lrow = 0.f;

    us8 r0, r1;
    {
        const us8* p = (const us8*)gsrc;
        r0 = p[0]; r1 = p[1];
        if (kside) {
            *(us8*)&Ks[0][sr * 72 + sc] = r0;
            *(us8*)&Ks[0][sr * 72 + sc + 8] = r1;
        } else {
#pragma unroll
            for (int i = 0; i < 8; ++i) {
                int d0 = sc + i, d1 = sc + 8 + i;
                Vts[0][d0 * 72 + (sr ^ (((d0 >> 4) & 3) << 4))] = r0[i];
                Vts[0][d1 * 72 + (sr ^ (((d1 >> 4) & 3) << 4))] = r1[i];
            }
        }
    }
    __syncthreads();

    int qmax = qt * 128 + w * 16 + 15;
    int NTk = 2 * qt + 2;
    for (int kt = 0; kt < NTk; ++kt) {
        int cur = kt & 1;
        bool pre = (kt + 1 < NTk);
        if (pre) {
            const us8* p = (const us8*)(gsrc + (size_t)(kt + 1) * 64 * 2304);
            r0 = p[0]; r1 = p[1];
        }

        if (kt * 64 <= qmax) {
            f32x4 accs[4];
#pragma unroll
            for (int n = 0; n < 4; ++n)
#pragma unroll
                for (int r = 0; r < 4; ++r) accs[n][r] = 0.f;
            {
                bf16x8 kf0[4], kf1[4];
#pragma unroll
                for (int n = 0; n < 4; ++n) {
                    kf0[n] = *(const bf16x8*)&Ks[cur][(n * 16 + fr) * 72 + fq * 8];
                    kf1[n] = *(const bf16x8*)&Ks[cur][(n * 16 + fr) * 72 + 32 + fq * 8];
                }
                __builtin_amdgcn_s_setprio(1);
#pragma unroll
                for (int n = 0; n < 4; ++n) {
                    accs[n] = __builtin_amdgcn_mfma_f32_16x16x32_bf16(kf0[n], qf0, accs[n], 0, 0, 0);
                    accs[n] = __builtin_amdgcn_mfma_f32_16x16x32_bf16(kf1[n], qf1, accs[n], 0, 0, 0);
                }
                __builtin_amdgcn_s_setprio(0);
            }

            bool diag = (kt * 64 + 63 > qt * 128 + w * 16);
#pragma unroll
            for (int n = 0; n < 4; ++n) {
                ushort4 pw;
                unsigned short* pwp = (unsigned short*)&pw;
#pragma unroll
                for (int r = 0; r < 4; ++r) {
                    float s = accs[n][r] * 0.125f;
                    if (diag) { int j = kt * 64 + n * 16 + fq * 4 + r; if (j > qrow) s = -1e30f; }
                    float p = __expf(s);
                    lrow += p;
                    pwp[r] = f2bf(p);
                }
                *(ushort4*)&Ps[(w * 16 + fr) * 72 + n * 16 + fq * 4] = pw;
            }

            {
                bf16x8 pf0 = *(const bf16x8*)&Ps[(w * 16 + fr) * 72 + fq * 8];
                bf16x8 pf1 = *(const bf16x8*)&Ps[(w * 16 + fr) * 72 + 32 + fq * 8];
                bf16x8 vf0[4], vf1[4];
#pragma unroll
                for (int n = 0; n < 4; ++n) {
                    int cA = (fq * 8) ^ (n << 4);
                    int cB = (32 + fq * 8) ^ (n << 4);
                    vf0[n] = *(const bf16x8*)&Vts[cur][(n * 16 + fr) * 72 + cA];
                    vf1[n] = *(const bf16x8*)&Vts[cur][(n * 16 + fr) * 72 + cB];
                }
                __builtin_amdgcn_s_setprio(1);
#pragma unroll
                for (int n = 0; n < 4; ++n) {
                    acco[n] = __builtin_amdgcn_mfma_f32_16x16x32_bf16(vf0[n], pf0, acco[n], 0, 0, 0);
                    acco[n] = __builtin_amdgcn_mfma_f32_16x16x32_bf16(vf1[n], pf1, acco[n], 0, 0, 0);
                }
                __builtin_amdgcn_s_setprio(0);
            }
        }

        if (pre) {
            if (kside) {
                *(us8*)&Ks[cur ^ 1][sr * 72 + sc] = r0;
                *(us8*)&Ks[cur ^ 1][sr * 72 + sc + 8] = r1;
            } else {
#pragma unroll
                for (int i = 0; i < 8; ++i) {
                    int d0 = sc + i, d1 = sc + 8 + i;
                    Vts[cur ^ 1][d0 * 72 + (sr ^ (((d0 >> 4) & 3) << 4))] = r0[i];
                    Vts[cur ^ 1][d1 * 72 + (sr ^ (((d1 >> 4) & 3) << 4))] = r1[i];
                }
            }
        }
        __syncthreads();
    }

    lrow += __shfl_xor(lrow, 16);
    lrow += __shfl_xor(lrow, 32);
    float inv = 1.0f / lrow;

    unsigned short* yp = y + (size_t)(b * TT + qrow) * NN + h * 64;
#pragma unroll
    for (int n = 0; n < 4; ++n) {
        ushort4 u;
        u.x = f2bf(acco[n][0] * inv);
        u.y = f2bf(acco[n][1] * inv);
        u.z = f2bf(acco[n][2] * inv);
        u.w = f2bf(acco[n][3] * inv);
        *(ushort4*)&yp[n * 16 + fq * 4] = u;
    }
}

// ---------------- logits with fused final LN ----------------
__global__ __launch_bounds__(256) void logits_kernel(const float* __restrict__ hf,
                                                     const float* __restrict__ lnw,
                                                     const float* __restrict__ wte,
                                                     float* __restrict__ out)
{
    __shared__ float hl[BB][NN];
    int wv = threadIdx.x >> 6, lane = threadIdx.x & 63;
    for (int rr = wv; rr < BB; rr += 4) {
        const float* src = hf + (size_t)(rr * TT + TT - 1) * NN;
        float4 v[3]; float s = 0.f, ss = 0.f;
#pragma unroll
        for (int i = 0; i < 3; ++i) {
            int c = (lane + i * 64) * 4;
            v[i] = *(const float4*)&src[c];
            s  += v[i].x + v[i].y + v[i].z + v[i].w;
            ss += v[i].x * v[i].x + v[i].y * v[i].y + v[i].z * v[i].z + v[i].w * v[i].w;
        }
#pragma unroll
        for (int off = 32; off; off >>= 1) { s += __shfl_xor(s, off); ss += __shfl_xor(ss, off); }
        float mu = s / (float)NN;
        float rsig = rsqrtf(ss / (float)NN - mu * mu + 1e-5f);
#pragma unroll
        for (int i = 0; i < 3; ++i) {
            int c = (lane + i * 64) * 4;
            float4 wv4 = *(const float4*)&lnw[c];
            float4 o;
            o.x = (v[i].x - mu) * rsig * wv4.x;
            o.y = (v[i].y - mu) * rsig * wv4.y;
            o.z = (v[i].z - mu) * rsig * wv4.z;
            o.w = (v[i].w - mu) * rsig * wv4.w;
            *(float4*)&hl[rr][c] = o;
        }
    }
    __syncthreads();

    const int NCH = (VV + 3) / 4;
    for (int cid = blockIdx.x * 4 + wv; cid < NCH; cid += gridDim.x * 4) {
        int v0 = cid * 4;
        float4 wv4[4][3];
#pragma unroll
        for (int r = 0; r < 4; ++r) {
            int v = min(v0 + r, VV - 1);
            const float4* wr4 = (const float4*)(wte + (size_t)v * NN);
#pragma unroll
            for (int i = 0; i < 3; ++i) wv4[r][i] = wr4[i * 64 + lane];
        }
        float acc[4][BB];
#pragma unroll
        for (int r = 0; r < 4; ++r)
#pragma unroll
            for (int b = 0; b < BB; ++b) acc[r][b] = 0.f;
#pragma unroll
        for (int i = 0; i < 3; ++i) {
#pragma unroll
            for (int b = 0; b < BB; ++b) {
                float4 h4 = *(const float4*)&hl[b][i * 256 + lane * 4];
#pragma unroll
                for (int r = 0; r < 4; ++r)
                    acc[r][b] += wv4[r][i].x * h4.x + wv4[r][i].y * h4.y
                               + wv4[r][i].z * h4.z + wv4[r][i].w * h4.w;
            }
        }
#pragma unroll
        for (int off = 32; off; off >>= 1)
#pragma unroll
            for (int r = 0; r < 4; ++r)
#pragma unroll
                for (int b = 0; b < BB; ++b) acc[r][b] += __shfl_xor(acc[r][b], off);
        if (lane == 0) {
#pragma unroll
            for (int r = 0; r < 4; ++r) {
                int v = v0 + r;
                if (v < VV)
#pragma unroll
                    for (int b = 0; b < BB; ++b) out[(size_t)b * VV + v] = acc[r][b];
            }
        }
    }
}

extern "C" void kernel_launch(void* const* d_in, const int* in_sizes, int n_in,
                              void* d_out, int out_size, void* d_ws, size_t ws_size,
                              hipStream_t stream) {
    const int*   idx       = (const int*)d_in[0];
    const float* wte       = (const float*)d_in[1];
    const float* wpe       = (const float*)d_in[2];
    const float* step_emb  = (const float*)d_in[3];
    const float* ln1_w     = (const float*)d_in[4];
    const float* ln2_w     = (const float*)d_in[5];
    const float* lnf_w     = (const float*)d_in[6];
    const float* c_attn    = (const float*)d_in[7];
    const float* attn_proj = (const float*)d_in[8];
    const float* c_fc      = (const float*)d_in[9];
    const float* mlp_proj  = (const float*)d_in[10];
    float* out = (float*)d_out;

    float* ws = (float*)d_ws;
    const size_t RC = (size_t)MM * NN;
    float* x0  = ws;
    float* hin = ws + RC;
    unsigned short* big = (unsigned short*)(ws + 2 * RC);
    unsigned short* lnb = (unsigned short*)(ws + 2 * RC + (size_t)MM * 3072 / 2);
    unsigned short* yb       = lnb + RC;
    unsigned short* cattn_bt = yb + RC;
    unsigned short* aproj_bt = cattn_bt + (size_t)2304 * 768;
    unsigned short* cfc_bt   = aproj_bt + (size_t)768 * 768;
    unsigned short* mproj_bt = cfc_bt + (size_t)768 * 3072;

    wconv_all<<<6912, 256, 0, stream>>>(c_attn, attn_proj, c_fc, mlp_proj,
                                        cattn_bt, aproj_bt, cfc_bt, mproj_bt);

    embed_kernel<<<MM / 8, 512, 0, stream>>>(idx, wte, wpe, step_emb, x0, hin);

    for (int l = 0; l < LL; ++l) {
        ln_kernel<<<MM / 8, 512, 0, stream>>>(hin, ln1_w, lnb);
        mgemm<128, 0, unsigned short><<<dim3(2304 / 128, MM / 128), 256, 0, stream>>>(
            lnb, cattn_bt, nullptr, big, 2304, 768, nullptr, nullptr);
        fattn_kernel<<<dim3(TT / 128, HH, BB), 512, 0, stream>>>(big, yb);
        mgemm<64, 2, float><<<dim3(768 / 64, MM / 128), 256, 0, stream>>>(
            yb, aproj_bt, hin, hin, 768, 768, nullptr, nullptr);
        ln_kernel<<<MM / 8, 512, 0, stream>>>(hin, ln2_w, lnb);
        mgemm<128, 1, unsigned short><<<dim3(3072 / 128, MM / 128), 256, 0, stream>>>(
            lnb, cfc_bt, nullptr, big, 3072, 768, nullptr, nullptr);
        if (l + 1 < LL) {
            mgemm<64, 3, float><<<dim3(768 / 64, MM / 128), 256, 0, stream>>>(
                big, mproj_bt, hin, hin, 768, 3072, x0, step_emb + (l + 1) * NN);
        } else {
            mgemm<64, 2, float><<<dim3(768 / 64, MM / 128), 256, 0, stream>>>(
                big, mproj_bt, hin, hin, 768, 3072, nullptr, nullptr);
        }
    }

    logits_kernel<<<1024, 256, 0, stream>>>(hin, lnf_w, wte, out);
}

// Round 14
// 1819.730 us; speedup vs baseline: 1.0439x; 1.0439x over previous
//
#include <hip/hip_runtime.h>
#include <hip/hip_bf16.h>
#include <math.h>

#define BB 8
#define TT 512
#define VV 50257
#define NN 768
#define HH 12
#define LL 12
#define MM (BB*TT)   // 4096 rows

typedef short bf16x8 __attribute__((ext_vector_type(8)));
typedef float f32x4 __attribute__((ext_vector_type(4)));
typedef unsigned short us8 __attribute__((ext_vector_type(8)));

__device__ __forceinline__ float bf2f(unsigned short u) {
    union { unsigned int i; float f; } x; x.i = ((unsigned int)u) << 16; return x.f;
}
__device__ __forceinline__ unsigned short f2bf(float f) {
    union { __hip_bfloat16 h; unsigned short u; } c; c.h = __float2bfloat16(f); return c.u;
}

// exact-GELU via A&S 7.1.26 erf (|err|<=1.5e-7, branch-free)
__device__ __forceinline__ float gelu_f(float v) {
    float z = v * 0.70710678118654752f;
    float az = fabsf(z);
    float t = __builtin_amdgcn_rcpf(1.0f + 0.3275911f * az);
    float poly = t * (0.254829592f + t * (-0.284496736f + t * (1.421413741f
               + t * (-1.453152027f + t * 1.061405429f))));
    float erfa = 1.0f - poly * __expf(-z * z);
    float erfv = copysignf(erfa, z);
    return 0.5f * v * (1.0f + erfv);
}

// ---------------- embedding: x0 = wte[idx]+wpe ; hin0 = 2*x0 + se0 ----------------
__global__ __launch_bounds__(512) void embed_kernel(const int* __restrict__ idx,
                                                    const float* __restrict__ wte,
                                                    const float* __restrict__ wpe,
                                                    const float* __restrict__ se0,
                                                    float* __restrict__ x0,
                                                    float* __restrict__ hin)
{
    int row = blockIdx.x * 8 + (threadIdx.x >> 6);
    int lane = threadIdx.x & 63;
    int t = row % TT;
    int tok = idx[row];
    const float* wt = wte + (size_t)tok * NN;
    const float* wp = wpe + (size_t)t * NN;
    float* px = x0 + (size_t)row * NN;
    float* ph = hin + (size_t)row * NN;
#pragma unroll
    for (int i = 0; i < 3; ++i) {
        int c = (lane + i * 64) * 4;
        float4 a = *(const float4*)&wt[c];
        float4 b = *(const float4*)&wp[c];
        float4 e = *(const float4*)&se0[c];
        float4 v = make_float4(a.x + b.x, a.y + b.y, a.z + b.z, a.w + b.w);
        *(float4*)&px[c] = v;
        float4 h2 = make_float4(2.f * v.x + e.x, 2.f * v.y + e.y,
                                2.f * v.z + e.z, 2.f * v.w + e.w);
        *(float4*)&ph[c] = h2;
    }
}

// ---------------- merged weight convert+transpose ----------------
__global__ __launch_bounds__(256) void wconv_all(
    const float* __restrict__ c_attn, const float* __restrict__ attn_proj,
    const float* __restrict__ c_fc, const float* __restrict__ mlp_proj,
    unsigned short* __restrict__ o1, unsigned short* __restrict__ o2,
    unsigned short* __restrict__ o3, unsigned short* __restrict__ o4)
{
    int bid = blockIdx.x;
    const float* W; unsigned short* Wt; int K, Nc, id;
    if (bid < 1728)      { W = c_attn;    Wt = o1; K = 768;  Nc = 2304; id = bid; }
    else if (bid < 2304) { W = attn_proj; Wt = o2; K = 768;  Nc = 768;  id = bid - 1728; }
    else if (bid < 4608) { W = c_fc;      Wt = o3; K = 768;  Nc = 3072; id = bid - 2304; }
    else                 { W = mlp_proj;  Wt = o4; K = 3072; Nc = 768;  id = bid - 4608; }
    int nbx = Nc / 32;
    int n0 = (id % nbx) * 32, k0 = (id / nbx) * 32;

    __shared__ float tile[32][33];
    int tid = threadIdx.x;
    int r = tid >> 3, c4 = (tid & 7) * 4;
    float4 v = *(const float4*)&W[(size_t)(k0 + r) * Nc + n0 + c4];
    tile[r][c4 + 0] = v.x; tile[r][c4 + 1] = v.y;
    tile[r][c4 + 2] = v.z; tile[r][c4 + 3] = v.w;
    __syncthreads();
    ushort4 o;
    o.x = f2bf(tile[c4 + 0][r]); o.y = f2bf(tile[c4 + 1][r]);
    o.z = f2bf(tile[c4 + 2][r]); o.w = f2bf(tile[c4 + 3][r]);
    *(ushort4*)&Wt[(size_t)(n0 + r) * K + k0 + c4] = o;
}

// ---------------- plain layernorm: 1 wave/row, 8 rows/block ----------------
__global__ __launch_bounds__(512) void ln_kernel(
    const float* __restrict__ src, const float* __restrict__ w,
    unsigned short* __restrict__ out)
{
    int row = blockIdx.x * 8 + (threadIdx.x >> 6);
    int lane = threadIdx.x & 63;
    size_t base = (size_t)row * NN;
    float4 v[3];
    float s = 0.f, ss = 0.f;
#pragma unroll
    for (int i = 0; i < 3; ++i) {
        int c = (lane + i * 64) * 4;
        v[i] = *(const float4*)&src[base + c];
        s  += v[i].x + v[i].y + v[i].z + v[i].w;
        ss += v[i].x * v[i].x + v[i].y * v[i].y + v[i].z * v[i].z + v[i].w * v[i].w;
    }
#pragma unroll
    for (int off = 32; off; off >>= 1) { s += __shfl_xor(s, off); ss += __shfl_xor(ss, off); }
    float mu = s / (float)NN;
    float var = ss / (float)NN - mu * mu;
    float rsig = rsqrtf(var + 1e-5f);
#pragma unroll
    for (int i = 0; i < 3; ++i) {
        int c = (lane + i * 64) * 4;
        float4 wv = *(const float4*)&w[c];
        ushort4 u;
        u.x = f2bf((v[i].x - mu) * rsig * wv.x);
        u.y = f2bf((v[i].y - mu) * rsig * wv.y);
        u.z = f2bf((v[i].z - mu) * rsig * wv.z);
        u.w = f2bf((v[i].w - mu) * rsig * wv.w);
        *(ushort4*)&out[base + c] = u;
    }
}

// ---------------- bf16 MFMA GEMM: 3-buffer, depth-1, single barrier, XCD swizzle ----------------
// EPI: 0 none, 1 gelu, 2 C=res+AB, 3 C=res+AB+x0+se
template<int BN, int EPI, typename OutT>
__global__ __launch_bounds__(256) void mgemm(
    const unsigned short* __restrict__ A, const unsigned short* __restrict__ Bt,
    const float* __restrict__ res, OutT* __restrict__ C, int N, int K,
    const float* __restrict__ x0p, const float* __restrict__ sep)
{
    constexpr int NF = BN / 32;
    __shared__ unsigned short Asb[3][128 * 32];
    __shared__ unsigned short Bsb[3][BN * 32];
    int tid = threadIdx.x;

    int gx = gridDim.x, nwg = gx * gridDim.y;
    int bidl = blockIdx.y * gx + blockIdx.x;
    int cpx = nwg >> 3;
    int sbid = (bidl & 7) * cpx + (bidl >> 3);
    int bx = sbid % gx, by = sbid / gx;

    int row0 = by * 128, col0 = bx * BN;
    const unsigned short* Ap = A + (size_t)row0 * K;
    const unsigned short* Bp = Bt + (size_t)col0 * K;
    int lane = tid & 63, wid = tid >> 6;
    int wr = wid >> 1, wc = wid & 1;
    int fr = lane & 15, fq = lane >> 4;

    f32x4 acc[4][NF];
#pragma unroll
    for (int m = 0; m < 4; ++m)
#pragma unroll
        for (int n = 0; n < NF; ++n)
#pragma unroll
            for (int r = 0; r < 4; ++r) acc[m][n][r] = 0.f;

    int ldso = (tid & 192) * 8;

    auto STAGE = [&](int buf, int k0) {
#pragma unroll
        for (int i = 0; i < 2; ++i) {
            int c = i * 256 + tid;
            __builtin_amdgcn_global_load_lds(
                (const __attribute__((address_space(1))) void*)(Ap + (size_t)(c >> 2) * K + k0 + (c & 3) * 8),
                (__attribute__((address_space(3))) void*)(Asb[buf] + i * 2048 + ldso), 16, 0, 0);
        }
        if constexpr (BN == 128) {
#pragma unroll
            for (int i = 0; i < 2; ++i) {
                int c = i * 256 + tid;
                __builtin_amdgcn_global_load_lds(
                    (const __attribute__((address_space(1))) void*)(Bp + (size_t)(c >> 2) * K + k0 + (c & 3) * 8),
                    (__attribute__((address_space(3))) void*)(Bsb[buf] + i * 2048 + ldso), 16, 0, 0);
            }
        } else {
            __builtin_amdgcn_global_load_lds(
                (const __attribute__((address_space(1))) void*)(Bp + (size_t)(tid >> 2) * K + k0 + (tid & 3) * 8),
                (__attribute__((address_space(3))) void*)(Bsb[buf] + ldso), 16, 0, 0);
        }
    };

    auto COMPUTE = [&](int buf) {
        const unsigned short* Ab = Asb[buf] + (wr * 64 + fr) * 32 + fq * 8;
        const unsigned short* Bb = Bsb[buf] + (wc * (BN / 2) + fr) * 32 + fq * 8;
        bf16x8 af[4], bfr[NF];
#pragma unroll
        for (int m = 0; m < 4; ++m) af[m] = *(const bf16x8*)(Ab + m * 512);
#pragma unroll
        for (int n = 0; n < NF; ++n) bfr[n] = *(const bf16x8*)(Bb + n * 512);
        __builtin_amdgcn_s_setprio(1);
#pragma unroll
        for (int m = 0; m < 4; ++m)
#pragma unroll
            for (int n = 0; n < NF; ++n)
                acc[m][n] = __builtin_amdgcn_mfma_f32_16x16x32_bf16(af[m], bfr[n], acc[m][n], 0, 0, 0);
        __builtin_amdgcn_s_setprio(0);
    };

    int NT = K / 32;
    STAGE(0, 0);
    for (int t = 0; t < NT; ++t) {
        if (t + 1 < NT) {
            STAGE((t + 1) % 3, (t + 1) * 32);
            if constexpr (BN == 128) asm volatile("s_waitcnt vmcnt(4)" ::: "memory");
            else                     asm volatile("s_waitcnt vmcnt(3)" ::: "memory");
        } else {
            asm volatile("s_waitcnt vmcnt(0)" ::: "memory");
        }
        __builtin_amdgcn_s_barrier();
        COMPUTE(t % 3);
    }

#pragma unroll
    for (int m = 0; m < 4; ++m) {
#pragma unroll
        for (int n = 0; n < NF; ++n) {
            int col = col0 + wc * (BN / 2) + n * 16 + fr;
#pragma unroll
            for (int r = 0; r < 4; ++r) {
                int row = row0 + wr * 64 + m * 16 + fq * 4 + r;
                float v = acc[m][n][r];
                if (EPI == 1) v = gelu_f(v);
                if (EPI == 2) v += res[(size_t)row * N + col];
                if (EPI == 3) v += res[(size_t)row * N + col] + x0p[(size_t)row * N + col] + sep[col];
                if constexpr (sizeof(OutT) == 2) C[(size_t)row * N + col] = (OutT)f2bf(v);
                else C[(size_t)row * N + col] = v;
            }
        }
    }
}

// ---------------- flash MFMA attention: transposed S/O via MFMA operand swap ----------------
__global__ __launch_bounds__(512) void fattn_kernel(const unsigned short* __restrict__ qkv,
                                                    unsigned short* __restrict__ y)
{
    int qt = blockIdx.x, h = blockIdx.y, b = blockIdx.z;
    int tid = threadIdx.x, lane = tid & 63, w = tid >> 6;
    int fr = lane & 15, fq = lane >> 4;

    __shared__ unsigned short Ks[2][64 * 72];
    __shared__ unsigned short Vts[2][64 * 72];
    __shared__ unsigned short Ps[128 * 72];

    int qrow = qt * 128 + w * 16 + fr;
    const unsigned short* qp = qkv + (size_t)(b * TT + qrow) * 2304 + h * 64 + fq * 8;
    bf16x8 qf0 = *(const bf16x8*)qp;
    bf16x8 qf1 = *(const bf16x8*)(qp + 32);

    bool kside = tid < 256;
    int st = tid & 255;
    int sr = st >> 2, sc = (st & 3) * 16;
    const unsigned short* gsrc = qkv + (size_t)(b * TT + sr) * 2304 + (kside ? 768 : 1536) + h * 64 + sc;

    f32x4 acco[4];
#pragma unroll
    for (int n = 0; n < 4; ++n)
#pragma unroll
        for (int r = 0; r < 4; ++r) acco[n][r] = 0.f;
    float lrow = 0.f;

    us8 r0, r1;
    {
        const us8* p = (const us8*)gsrc;
        r0 = p[0]; r1 = p[1];
        if (kside) {
            *(us8*)&Ks[0][sr * 72 + sc] = r0;
            *(us8*)&Ks[0][sr * 72 + sc + 8] = r1;
        } else {
#pragma unroll
            for (int i = 0; i < 8; ++i) {
                int d0 = sc + i, d1 = sc + 8 + i;
                Vts[0][d0 * 72 + (sr ^ (((d0 >> 4) & 3) << 4))] = r0[i];
                Vts[0][d1 * 72 + (sr ^ (((d1 >> 4) & 3) << 4))] = r1[i];
            }
        }
    }
    __syncthreads();

    int qmax = qt * 128 + w * 16 + 15;
    int NTk = 2 * qt + 2;
    for (int kt = 0; kt < NTk; ++kt) {
        int cur = kt & 1;
        bool pre = (kt + 1 < NTk);
        if (pre) {
            const us8* p = (const us8*)(gsrc + (size_t)(kt + 1) * 64 * 2304);
            r0 = p[0]; r1 = p[1];
        }

        if (kt * 64 <= qmax) {
            f32x4 accs[4];
#pragma unroll
            for (int n = 0; n < 4; ++n)
#pragma unroll
                for (int r = 0; r < 4; ++r) accs[n][r] = 0.f;
            {
                bf16x8 kf0[4], kf1[4];
#pragma unroll
                for (int n = 0; n < 4; ++n) {
                    kf0[n] = *(const bf16x8*)&Ks[cur][(n * 16 + fr) * 72 + fq * 8];
                    kf1[n] = *(const bf16x8*)&Ks[cur][(n * 16 + fr) * 72 + 32 + fq * 8];
                }
                __builtin_amdgcn_s_setprio(1);
#pragma unroll
                for (int n = 0; n < 4; ++n) {
                    accs[n] = __builtin_amdgcn_mfma_f32_16x16x32_bf16(kf0[n], qf0, accs[n], 0, 0, 0);
                    accs[n] = __builtin_amdgcn_mfma_f32_16x16x32_bf16(kf1[n], qf1, accs[n], 0, 0, 0);
                }
                __builtin_amdgcn_s_setprio(0);
            }

            bool diag = (kt * 64 + 63 > qt * 128 + w * 16);
#pragma unroll
            for (int n = 0; n < 4; ++n) {
                ushort4 pw;
                unsigned short* pwp = (unsigned short*)&pw;
#pragma unroll
                for (int r = 0; r < 4; ++r) {
                    float s = accs[n][r] * 0.125f;
                    if (diag) { int j = kt * 64 + n * 16 + fq * 4 + r; if (j > qrow) s = -1e30f; }
                    float p = __expf(s);
                    lrow += p;
                    pwp[r] = f2bf(p);
                }
                *(ushort4*)&Ps[(w * 16 + fr) * 72 + n * 16 + fq * 4] = pw;
            }

            {
                bf16x8 pf0 = *(const bf16x8*)&Ps[(w * 16 + fr) * 72 + fq * 8];
                bf16x8 pf1 = *(const bf16x8*)&Ps[(w * 16 + fr) * 72 + 32 + fq * 8];
                bf16x8 vf0[4], vf1[4];
#pragma unroll
                for (int n = 0; n < 4; ++n) {
                    int cA = (fq * 8) ^ (n << 4);
                    int cB = (32 + fq * 8) ^ (n << 4);
                    vf0[n] = *(const bf16x8*)&Vts[cur][(n * 16 + fr) * 72 + cA];
                    vf1[n] = *(const bf16x8*)&Vts[cur][(n * 16 + fr) * 72 + cB];
                }
                __builtin_amdgcn_s_setprio(1);
#pragma unroll
                for (int n = 0; n < 4; ++n) {
                    acco[n] = __builtin_amdgcn_mfma_f32_16x16x32_bf16(vf0[n], pf0, acco[n], 0, 0, 0);
                    acco[n] = __builtin_amdgcn_mfma_f32_16x16x32_bf16(vf1[n], pf1, acco[n], 0, 0, 0);
                }
                __builtin_amdgcn_s_setprio(0);
            }
        }

        if (pre) {
            if (kside) {
                *(us8*)&Ks[cur ^ 1][sr * 72 + sc] = r0;
                *(us8*)&Ks[cur ^ 1][sr * 72 + sc + 8] = r1;
            } else {
#pragma unroll
                for (int i = 0; i < 8; ++i) {
                    int d0 = sc + i, d1 = sc + 8 + i;
                    Vts[cur ^ 1][d0 * 72 + (sr ^ (((d0 >> 4) & 3) << 4))] = r0[i];
                    Vts[cur ^ 1][d1 * 72 + (sr ^ (((d1 >> 4) & 3) << 4))] = r1[i];
                }
            }
        }
        __syncthreads();
    }

    lrow += __shfl_xor(lrow, 16);
    lrow += __shfl_xor(lrow, 32);
    float inv = 1.0f / lrow;

    unsigned short* yp = y + (size_t)(b * TT + qrow) * NN + h * 64;
#pragma unroll
    for (int n = 0; n < 4; ++n) {
        ushort4 u;
        u.x = f2bf(acco[n][0] * inv);
        u.y = f2bf(acco[n][1] * inv);
        u.z = f2bf(acco[n][2] * inv);
        u.w = f2bf(acco[n][3] * inv);
        *(ushort4*)&yp[n * 16 + fq * 4] = u;
    }
}

// ---------------- logits with fused final LN ----------------
__global__ __launch_bounds__(256) void logits_kernel(const float* __restrict__ hf,
                                                     const float* __restrict__ lnw,
                                                     const float* __restrict__ wte,
                                                     float* __restrict__ out)
{
    __shared__ float hl[BB][NN];
    int wv = threadIdx.x >> 6, lane = threadIdx.x & 63;
    for (int rr = wv; rr < BB; rr += 4) {
        const float* src = hf + (size_t)(rr * TT + TT - 1) * NN;
        float4 v[3]; float s = 0.f, ss = 0.f;
#pragma unroll
        for (int i = 0; i < 3; ++i) {
            int c = (lane + i * 64) * 4;
            v[i] = *(const float4*)&src[c];
            s  += v[i].x + v[i].y + v[i].z + v[i].w;
            ss += v[i].x * v[i].x + v[i].y * v[i].y + v[i].z * v[i].z + v[i].w * v[i].w;
        }
#pragma unroll
        for (int off = 32; off; off >>= 1) { s += __shfl_xor(s, off); ss += __shfl_xor(ss, off); }
        float mu = s / (float)NN;
        float rsig = rsqrtf(ss / (float)NN - mu * mu + 1e-5f);
#pragma unroll
        for (int i = 0; i < 3; ++i) {
            int c = (lane + i * 64) * 4;
            float4 wv4 = *(const float4*)&lnw[c];
            float4 o;
            o.x = (v[i].x - mu) * rsig * wv4.x;
            o.y = (v[i].y - mu) * rsig * wv4.y;
            o.z = (v[i].z - mu) * rsig * wv4.z;
            o.w = (v[i].w - mu) * rsig * wv4.w;
            *(float4*)&hl[rr][c] = o;
        }
    }
    __syncthreads();

    const int NCH = (VV + 3) / 4;
    for (int cid = blockIdx.x * 4 + wv; cid < NCH; cid += gridDim.x * 4) {
        int v0 = cid * 4;
        float4 wv4[4][3];
#pragma unroll
        for (int r = 0; r < 4; ++r) {
            int v = min(v0 + r, VV - 1);
            const float4* wr4 = (const float4*)(wte + (size_t)v * NN);
#pragma unroll
            for (int i = 0; i < 3; ++i) wv4[r][i] = wr4[i * 64 + lane];
        }
        float acc[4][BB];
#pragma unroll
        for (int r = 0; r < 4; ++r)
#pragma unroll
            for (int b = 0; b < BB; ++b) acc[r][b] = 0.f;
#pragma unroll
        for (int i = 0; i < 3; ++i) {
#pragma unroll
            for (int b = 0; b < BB; ++b) {
                float4 h4 = *(const float4*)&hl[b][i * 256 + lane * 4];
#pragma unroll
                for (int r = 0; r < 4; ++r)
                    acc[r][b] += wv4[r][i].x * h4.x + wv4[r][i].y * h4.y
                               + wv4[r][i].z * h4.z + wv4[r][i].w * h4.w;
            }
        }
#pragma unroll
        for (int off = 32; off; off >>= 1)
#pragma unroll
            for (int r = 0; r < 4; ++r)
#pragma unroll
                for (int b = 0; b < BB; ++b) acc[r][b] += __shfl_xor(acc[r][b], off);
        if (lane == 0) {
#pragma unroll
            for (int r = 0; r < 4; ++r) {
                int v = v0 + r;
                if (v < VV)
#pragma unroll
                    for (int b = 0; b < BB; ++b) out[(size_t)b * VV + v] = acc[r][b];
            }
        }
    }
}

extern "C" void kernel_launch(void* const* d_in, const int* in_sizes, int n_in,
                              void* d_out, int out_size, void* d_ws, size_t ws_size,
                              hipStream_t stream) {
    const int*   idx       = (const int*)d_in[0];
    const float* wte       = (const float*)d_in[1];
    const float* wpe       = (const float*)d_in[2];
    const float* step_emb  = (const float*)d_in[3];
    const float* ln1_w     = (const float*)d_in[4];
    const float* ln2_w     = (const float*)d_in[5];
    const float* lnf_w     = (const float*)d_in[6];
    const float* c_attn    = (const float*)d_in[7];
    const float* attn_proj = (const float*)d_in[8];
    const float* c_fc      = (const float*)d_in[9];
    const float* mlp_proj  = (const float*)d_in[10];
    float* out = (float*)d_out;

    float* ws = (float*)d_ws;
    const size_t RC = (size_t)MM * NN;
    float* x0  = ws;
    float* hin = ws + RC;
    unsigned short* big = (unsigned short*)(ws + 2 * RC);
    unsigned short* lnb = (unsigned short*)(ws + 2 * RC + (size_t)MM * 3072 / 2);
    unsigned short* yb       = lnb + RC;
    unsigned short* cattn_bt = yb + RC;
    unsigned short* aproj_bt = cattn_bt + (size_t)2304 * 768;
    unsigned short* cfc_bt   = aproj_bt + (size_t)768 * 768;
    unsigned short* mproj_bt = cfc_bt + (size_t)768 * 3072;

    wconv_all<<<6912, 256, 0, stream>>>(c_attn, attn_proj, c_fc, mlp_proj,
                                        cattn_bt, aproj_bt, cfc_bt, mproj_bt);

    embed_kernel<<<MM / 8, 512, 0, stream>>>(idx, wte, wpe, step_emb, x0, hin);

    for (int l = 0; l < LL; ++l) {
        ln_kernel<<<MM / 8, 512, 0, stream>>>(hin, ln1_w, lnb);
        mgemm<128, 0, unsigned short><<<dim3(2304 / 128, MM / 128), 256, 0, stream>>>(
            lnb, cattn_bt, nullptr, big, 2304, 768, nullptr, nullptr);
        fattn_kernel<<<dim3(TT / 128, HH, BB), 512, 0, stream>>>(big, yb);
        mgemm<64, 2, float><<<dim3(768 / 64, MM / 128), 256, 0, stream>>>(
            yb, aproj_bt, hin, hin, 768, 768, nullptr, nullptr);
        ln_kernel<<<MM / 8, 512, 0, stream>>>(hin, ln2_w, lnb);
        mgemm<128, 1, unsigned short><<<dim3(3072 / 128, MM / 128), 256, 0, stream>>>(
            lnb, cfc_bt, nullptr, big, 3072, 768, nullptr, nullptr);
        if (l + 1 < LL) {
            mgemm<64, 3, float><<<dim3(768 / 64, MM / 128), 256, 0, stream>>>(
                big, mproj_bt, hin, hin, 768, 3072, x0, step_emb + (l + 1) * NN);
        } else {
            mgemm<64, 2, float><<<dim3(768 / 64, MM / 128), 256, 0, stream>>>(
                big, mproj_bt, hin, hin, 768, 3072, nullptr, nullptr);
        }
    }

    logits_kernel<<<1024, 256, 0, stream>>>(hin, lnf_w, wte, out);
}